// Round 8
// baseline (287.152 us; speedup 1.0000x reference)
//
#include <hip/hip_runtime.h>
#include <hip/hip_cooperative_groups.h>

namespace cg = cooperative_groups;

#define D_FEAT 64
#define NEG_INF_BITS 0xFF800000u
#define ENC_NEG_INF  0x007FFFFFu   // order-preserving encoding of -inf
#define NPB 128                     // nodes per bucket (= 1 << BSHIFT)
#define BSHIFT 7
#define BM_BLOCK 512                // bucket_max threads (8 waves)
#define MAXB 1024                   // max buckets
#define PP_BLOCK 512                // preprocess threads (8 waves)
#define PP_WAVES (PP_BLOCK / 64)

// Order-preserving float->uint: enc monotone increasing with float value.
__device__ __forceinline__ unsigned enc_f32(float v) {
    unsigned b = __float_as_uint(v);
    return ((int)b >= 0) ? (b ^ 0x80000000u) : ~b;
}
__device__ __forceinline__ float dec_f32(unsigned u) {
    return (u & 0x80000000u) ? __uint_as_float(u ^ 0x80000000u) : __uint_as_float(~u);
}

// ---------- fused preprocess: count -> colscan -> (local scan) place ----------
// Grid must be fully co-resident (T blocks x 512 thr, 2 blocks/CU at T=512).
__global__ void __launch_bounds__(PP_BLOCK)
preprocess_kernel(const int* __restrict__ src, const int* __restrict__ dst,
                  int* __restrict__ counts, int* __restrict__ hist,
                  int* __restrict__ bucket_start, unsigned* __restrict__ packed,
                  int E, int Te, int T, int B) {
    cg::grid_group grid = cg::this_grid();
    __shared__ int sm[MAXB];               // P1: local hist, P3: cursors
    __shared__ int part[PP_WAVES][64];     // P2 partials
    __shared__ int sscan[2 * PP_BLOCK];    // P3 local scan (1024 slots)

    int t = blockIdx.x;
    int tid = threadIdx.x;
    int beg = t * Te;
    int end = min(E, beg + Te);

    // ---- P1: per-tile histogram (LDS atomics only) ----
    for (int i = tid; i < B; i += PP_BLOCK) sm[i] = 0;
    __syncthreads();
    if ((E & 3) == 0) {
        int n4 = (end > beg) ? ((end - beg) >> 2) : 0;
        const int4* d4 = (const int4*)(dst + beg);     // beg multiple of 4
        for (int k = tid; k < n4; k += PP_BLOCK) {
            int4 d = d4[k];
            atomicAdd(&sm[d.x >> BSHIFT], 1);
            atomicAdd(&sm[d.y >> BSHIFT], 1);
            atomicAdd(&sm[d.z >> BSHIFT], 1);
            atomicAdd(&sm[d.w >> BSHIFT], 1);
        }
        for (int i = beg + (n4 << 2) + tid; i < end; i += PP_BLOCK)
            atomicAdd(&sm[dst[i] >> BSHIFT], 1);
    } else {
        for (int i = beg + tid; i < end; i += PP_BLOCK)
            atomicAdd(&sm[dst[i] >> BSHIFT], 1);
    }
    __syncthreads();
    for (int i = tid; i < B; i += PP_BLOCK) counts[t * B + i] = sm[i];

    grid.sync();

    // ---- P2: column exclusive scan over tiles (64 buckets per active block) ----
    int nbc = (B + 63) >> 6;
    if (t < nbc) {
        int lane = tid & 63;
        int wid = tid >> 6;
        int b = (t << 6) + lane;
        bool ok = b < B;
        int Tc = (T + PP_WAVES - 1) / PP_WAVES;
        int t0 = wid * Tc;
        int t1 = min(T, t0 + Tc);
        int s = 0;
        if (ok) {
            for (int tt = t0; tt < t1; ++tt) s += counts[tt * B + b];
        }
        part[wid][lane] = s;
        __syncthreads();
        int base = 0, total = 0;
        #pragma unroll
        for (int w = 0; w < PP_WAVES; ++w) {
            int pv = part[w][lane];
            if (w < wid) base += pv;
            total += pv;
        }
        if (ok) {
            if (wid == 0) hist[b] = total;
            int run = base;
            for (int tt = t0; tt < t1; ++tt) {
                int v = counts[tt * B + b];
                counts[tt * B + b] = run;
                run += v;
            }
        }
    }

    grid.sync();

    // ---- P3: every block locally scans hist (1024 slots, 2/thread), places tile ----
    int p0 = tid, p1 = tid + PP_BLOCK;
    int v0 = (p0 < B) ? hist[p0] : 0;
    int v1 = (p1 < B) ? hist[p1] : 0;
    sscan[p0] = v0;
    sscan[p1] = v1;
    __syncthreads();
    for (int off = 1; off < 2 * PP_BLOCK; off <<= 1) {
        int a0 = (p0 >= off) ? sscan[p0 - off] : 0;
        int a1 = (p1 >= off) ? sscan[p1 - off] : 0;
        __syncthreads();
        sscan[p0] += a0;
        sscan[p1] += a1;
        __syncthreads();
    }
    if (t == 0) {                              // publish bucket_start once
        if (p0 < B) bucket_start[p0] = sscan[p0] - v0;
        if (p1 < B) bucket_start[p1] = sscan[p1] - v1;
        if (tid == 0) bucket_start[B] = sscan[B - 1];
    }
    if (p0 < B) sm[p0] = (sscan[p0] - v0) + counts[t * B + p0];   // cursors
    if (p1 < B) sm[p1] = (sscan[p1] - v1) + counts[t * B + p1];
    __syncthreads();

    if ((E & 3) == 0) {
        int n4 = (end > beg) ? ((end - beg) >> 2) : 0;
        const int4* d4 = (const int4*)(dst + beg);
        const int4* s4 = (const int4*)(src + beg);
        for (int k = tid; k < n4; k += PP_BLOCK) {
            int4 d = d4[k];
            int4 s = s4[k];
            int q0 = atomicAdd(&sm[d.x >> BSHIFT], 1);
            packed[q0] = (unsigned)s.x | ((unsigned)(d.x & (NPB - 1)) << 17);
            int q1 = atomicAdd(&sm[d.y >> BSHIFT], 1);
            packed[q1] = (unsigned)s.y | ((unsigned)(d.y & (NPB - 1)) << 17);
            int q2 = atomicAdd(&sm[d.z >> BSHIFT], 1);
            packed[q2] = (unsigned)s.z | ((unsigned)(d.z & (NPB - 1)) << 17);
            int q3 = atomicAdd(&sm[d.w >> BSHIFT], 1);
            packed[q3] = (unsigned)s.w | ((unsigned)(d.w & (NPB - 1)) << 17);
        }
        for (int i = beg + (n4 << 2) + tid; i < end; i += PP_BLOCK) {
            int d = dst[i];
            int pos = atomicAdd(&sm[d >> BSHIFT], 1);
            packed[pos] = (unsigned)src[i] | ((unsigned)(d & (NPB - 1)) << 17);
        }
    } else {
        for (int i = beg + tid; i < end; i += PP_BLOCK) {
            int d = dst[i];
            int pos = atomicAdd(&sm[d >> BSHIFT], 1);
            packed[pos] = (unsigned)src[i] | ((unsigned)(d & (NPB - 1)) << 17);
        }
    }
}

// ---------- per-bucket scatter-max in LDS (round-5 winner, unchanged) ----------
__global__ void __launch_bounds__(BM_BLOCK)
bucket_max_kernel(const float* __restrict__ h,
                  const int* __restrict__ bucket_start,
                  const unsigned* __restrict__ packed,
                  float* __restrict__ out, int N) {
    __shared__ unsigned buf[NPB * D_FEAT];   // 32 KB
    int b = blockIdx.x;
    int tid = threadIdx.x;
    int node0 = b << BSHIFT;
    int nvals = (min(NPB, N - node0)) * D_FEAT;

    for (int i = tid; i < NPB * D_FEAT; i += BM_BLOCK) buf[i] = ENC_NEG_INF;
    __syncthreads();

    int beg = bucket_start[b];
    int end = bucket_start[b + 1];
    int wid = tid >> 6;
    int lane = tid & 63;

    for (int base = beg + (wid << 6); base < end; base += BM_BLOCK) {
        int nk = min(64, end - base);
        unsigned p = (lane < nk) ? packed[base + lane] : 0u;
        int j = 0;
        for (; j + 8 <= nk; j += 8) {
            unsigned q[8];
            float v[8];
            #pragma unroll
            for (int k = 0; k < 8; ++k) q[k] = (unsigned)__shfl((int)p, j + k);
            #pragma unroll
            for (int k = 0; k < 8; ++k) v[k] = h[(q[k] & 0x1FFFFu) * D_FEAT + lane];
            #pragma unroll
            for (int k = 0; k < 8; ++k)
                atomicMax(&buf[(q[k] >> 17) * D_FEAT + lane], enc_f32(v[k]));
        }
        for (; j < nk; ++j) {
            unsigned pj = (unsigned)__shfl((int)p, j);
            float v = h[(pj & 0x1FFFFu) * D_FEAT + lane];
            atomicMax(&buf[(pj >> 17) * D_FEAT + lane], enc_f32(v));
        }
    }
    __syncthreads();

    for (int i = tid; i < nvals; i += BM_BLOCK) {
        unsigned u = buf[i];
        out[node0 * D_FEAT + i] = (u == ENC_NEG_INF) ? 0.0f : dec_f32(u);
    }
}

// ---------- fallback: atomic scatter (round-1 path) ----------
__global__ void init_out_kernel(uint4* __restrict__ out, int n4) {
    int i = blockIdx.x * blockDim.x + threadIdx.x;
    if (i < n4) {
        uint4 v;
        v.x = NEG_INF_BITS; v.y = NEG_INF_BITS; v.z = NEG_INF_BITS; v.w = NEG_INF_BITS;
        out[i] = v;
    }
}
__global__ void scatter_max_kernel(const float* __restrict__ h, const int* __restrict__ src,
                                   const int* __restrict__ dst, float* __restrict__ out, int E) {
    int gid = blockIdx.x * blockDim.x + threadIdx.x;
    int e = gid >> 6;
    if (e >= E) return;
    int lane = gid & 63;
    float v = h[src[e] * D_FEAT + lane];
    int* addr = (int*)(out + dst[e] * D_FEAT + lane);
    if (v >= 0.0f) atomicMax(addr, __float_as_int(v));
    else           atomicMin((unsigned int*)addr, __float_as_uint(v));
}
__global__ void finalize_kernel(float* __restrict__ out, int n) {
    int i = blockIdx.x * blockDim.x + threadIdx.x;
    if (i < n && __float_as_uint(out[i]) == NEG_INF_BITS) out[i] = 0.0f;
}

// ---------- launch ----------
extern "C" void kernel_launch(void* const* d_in, const int* in_sizes, int n_in,
                              void* d_out, int out_size, void* d_ws, size_t ws_size,
                              hipStream_t stream) {
    const float* h = (const float*)d_in[0];
    const int* edge_index = (const int*)d_in[1];
    int E = in_sizes[1] / 2;                 // edge_index is [2, E] row-major
    const int* src = edge_index;
    const int* dst = edge_index + E;
    float* out = (float*)d_out;
    int N = out_size / D_FEAT;

    int B = (N + NPB - 1) >> BSHIFT;

    // largest fully-co-resident tile count whose workspace fits
    int T = 0;
    for (int cand = 512; cand >= 128; cand >>= 1) {
        size_t need = ((size_t)cand * B + B + (B + 1) + (size_t)E) * sizeof(int);
        if (ws_size >= need) { T = cand; break; }
    }

    if (N <= (1 << 17) && B <= MAXB && T > 0) {
        int* counts       = (int*)d_ws;                     // [T*B]
        int* hist         = counts + (size_t)T * B;         // [B]
        int* bucket_start = hist + B;                       // [B+1]
        unsigned* packed  = (unsigned*)(bucket_start + B + 1); // [E]

        int Te = ((E + T - 1) / T + 3) & ~3;                // tile size, mult of 4

        const int* src_p = src;
        const int* dst_p = dst;
        void* kargs[] = { (void*)&src_p, (void*)&dst_p, (void*)&counts, (void*)&hist,
                          (void*)&bucket_start, (void*)&packed,
                          (void*)&E, (void*)&Te, (void*)&T, (void*)&B };
        hipLaunchCooperativeKernel((const void*)preprocess_kernel, dim3(T), dim3(PP_BLOCK),
                                   kargs, 0, stream);

        bucket_max_kernel<<<B, BM_BLOCK, 0, stream>>>(h, bucket_start, packed, out, N);
    } else {
        int n4 = out_size / 4;
        init_out_kernel<<<(n4 + 255) / 256, 256, 0, stream>>>((uint4*)out, n4);
        long long total = (long long)E * 64;
        scatter_max_kernel<<<(int)((total + 255) / 256), 256, 0, stream>>>(h, src, dst, out, E);
        finalize_kernel<<<(out_size + 255) / 256, 256, 0, stream>>>(out, out_size);
    }
}

// Round 9
// 188.583 us; speedup vs baseline: 1.5227x; 1.5227x over previous
//
#include <hip/hip_runtime.h>

#define D_FEAT 64
#define NEG_INF_BITS 0xFF800000u
#define ENC_NEG_INF  0x007FFFFFu   // order-preserving encoding of -inf
#define NPB 128                     // nodes per bucket (= 1 << BSHIFT)
#define BSHIFT 7
#define BM_BLOCK 512                // bucket_max threads (8 waves)
#define PP_BLOCK 512                // count/place threads
#define MAXB 1024                   // max buckets (N <= 131072)

// Order-preserving float->uint: enc monotone increasing with float value.
__device__ __forceinline__ unsigned enc_f32(float v) {
    unsigned b = __float_as_uint(v);
    return ((int)b >= 0) ? (b ^ 0x80000000u) : ~b;
}
__device__ __forceinline__ float dec_f32(unsigned u) {
    return (u & 0x80000000u) ? __uint_as_float(u ^ 0x80000000u) : __uint_as_float(~u);
}

// ---------- K1: per-tile bucket histogram (LDS only, deterministic) ----------
__global__ void __launch_bounds__(PP_BLOCK)
count_kernel(const int* __restrict__ dst, int* __restrict__ counts,
             int E, int Te, int B) {
    __shared__ int lh[MAXB];
    int tid = threadIdx.x;
    for (int i = tid; i < B; i += PP_BLOCK) lh[i] = 0;
    __syncthreads();
    int t = blockIdx.x;
    int beg = t * Te;
    int end = min(E, beg + Te);
    if ((E & 3) == 0) {
        int n4 = (end > beg) ? ((end - beg) >> 2) : 0;
        const int4* d4 = (const int4*)(dst + beg);     // beg multiple of 4
        for (int k = tid; k < n4; k += PP_BLOCK) {
            int4 d = d4[k];
            atomicAdd(&lh[d.x >> BSHIFT], 1);
            atomicAdd(&lh[d.y >> BSHIFT], 1);
            atomicAdd(&lh[d.z >> BSHIFT], 1);
            atomicAdd(&lh[d.w >> BSHIFT], 1);
        }
        for (int i = beg + (n4 << 2) + tid; i < end; i += PP_BLOCK)
            atomicAdd(&lh[dst[i] >> BSHIFT], 1);
    } else {
        for (int i = beg + tid; i < end; i += PP_BLOCK)
            atomicAdd(&lh[dst[i] >> BSHIFT], 1);
    }
    __syncthreads();
    for (int i = tid; i < B; i += PP_BLOCK) counts[t * B + i] = lh[i];
}

// ---------- K2: column exclusive scan over tiles (64 buckets/block, coalesced) ----------
__global__ void __launch_bounds__(PP_BLOCK)
colscan_kernel(int* __restrict__ counts, int* __restrict__ hist, int T, int B) {
    __shared__ int part[PP_BLOCK / 64][64];
    int lane = threadIdx.x & 63;
    int wid = threadIdx.x >> 6;
    const int NW = PP_BLOCK / 64;
    int b = (blockIdx.x << 6) + lane;
    bool ok = b < B;
    int Tc = (T + NW - 1) / NW;
    int t0 = wid * Tc;
    int t1 = min(T, t0 + Tc);

    int s = 0;
    if (ok) {
        #pragma unroll 4
        for (int t = t0; t < t1; ++t) s += counts[t * B + b];
    }
    part[wid][lane] = s;
    __syncthreads();
    int base = 0, total = 0;
    #pragma unroll
    for (int w = 0; w < NW; ++w) {
        int pv = part[w][lane];
        if (w < wid) base += pv;
        total += pv;
    }
    if (ok) {
        if (wid == 0) hist[b] = total;
        int run = base;
        for (int t = t0; t < t1; ++t) {
            int v = counts[t * B + b];
            counts[t * B + b] = run;
            run += v;
        }
    }
}

// ---------- K3: place (local scan of hist -> cursors; LDS atomics only) ----------
__global__ void __launch_bounds__(PP_BLOCK)
place_kernel(const int* __restrict__ src, const int* __restrict__ dst,
             const int* __restrict__ counts, const int* __restrict__ hist,
             int* __restrict__ bucket_start, unsigned* __restrict__ packed,
             int E, int Te, int B) {
    __shared__ int sscan[2 * PP_BLOCK];    // 1024-slot local scan of hist
    __shared__ int lcur[MAXB];             // cursors
    int tid = threadIdx.x;
    int t = blockIdx.x;

    int p0 = tid, p1 = tid + PP_BLOCK;
    int v0 = (p0 < B) ? hist[p0] : 0;
    int v1 = (p1 < B) ? hist[p1] : 0;
    sscan[p0] = v0;
    sscan[p1] = v1;
    __syncthreads();
    for (int off = 1; off < 2 * PP_BLOCK; off <<= 1) {
        int a0 = (p0 >= off) ? sscan[p0 - off] : 0;
        int a1 = (p1 >= off) ? sscan[p1 - off] : 0;
        __syncthreads();
        sscan[p0] += a0;
        sscan[p1] += a1;
        __syncthreads();
    }
    if (t == 0) {                          // publish bucket_start once
        if (p0 < B) bucket_start[p0] = sscan[p0] - v0;
        if (p1 < B) bucket_start[p1] = sscan[p1] - v1;
        if (tid == 0) bucket_start[B] = sscan[B - 1];
    }
    if (p0 < B) lcur[p0] = (sscan[p0] - v0) + counts[t * B + p0];
    if (p1 < B) lcur[p1] = (sscan[p1] - v1) + counts[t * B + p1];
    __syncthreads();

    int beg = t * Te;
    int end = min(E, beg + Te);
    if ((E & 3) == 0) {
        int n4 = (end > beg) ? ((end - beg) >> 2) : 0;
        const int4* d4 = (const int4*)(dst + beg);
        const int4* s4 = (const int4*)(src + beg);
        for (int k = tid; k < n4; k += PP_BLOCK) {
            int4 d = d4[k];
            int4 s = s4[k];
            int q0 = atomicAdd(&lcur[d.x >> BSHIFT], 1);
            __builtin_nontemporal_store((unsigned)s.x | ((unsigned)(d.x & (NPB - 1)) << 17), &packed[q0]);
            int q1 = atomicAdd(&lcur[d.y >> BSHIFT], 1);
            __builtin_nontemporal_store((unsigned)s.y | ((unsigned)(d.y & (NPB - 1)) << 17), &packed[q1]);
            int q2 = atomicAdd(&lcur[d.z >> BSHIFT], 1);
            __builtin_nontemporal_store((unsigned)s.z | ((unsigned)(d.z & (NPB - 1)) << 17), &packed[q2]);
            int q3 = atomicAdd(&lcur[d.w >> BSHIFT], 1);
            __builtin_nontemporal_store((unsigned)s.w | ((unsigned)(d.w & (NPB - 1)) << 17), &packed[q3]);
        }
        for (int i = beg + (n4 << 2) + tid; i < end; i += PP_BLOCK) {
            int d = dst[i];
            int pos = atomicAdd(&lcur[d >> BSHIFT], 1);
            __builtin_nontemporal_store((unsigned)src[i] | ((unsigned)(d & (NPB - 1)) << 17), &packed[pos]);
        }
    } else {
        for (int i = beg + tid; i < end; i += PP_BLOCK) {
            int d = dst[i];
            int pos = atomicAdd(&lcur[d >> BSHIFT], 1);
            __builtin_nontemporal_store((unsigned)src[i] | ((unsigned)(d & (NPB - 1)) << 17), &packed[pos]);
        }
    }
}

// ---------- K4: per-bucket scatter-max in LDS (round-5 winner, unchanged) ----------
__global__ void __launch_bounds__(BM_BLOCK)
bucket_max_kernel(const float* __restrict__ h,
                  const int* __restrict__ bucket_start,
                  const unsigned* __restrict__ packed,
                  float* __restrict__ out, int N) {
    __shared__ unsigned buf[NPB * D_FEAT];   // 32 KB
    int b = blockIdx.x;
    int tid = threadIdx.x;
    int node0 = b << BSHIFT;
    int nvals = (min(NPB, N - node0)) * D_FEAT;

    for (int i = tid; i < NPB * D_FEAT; i += BM_BLOCK) buf[i] = ENC_NEG_INF;
    __syncthreads();

    int beg = bucket_start[b];
    int end = bucket_start[b + 1];
    int wid = tid >> 6;
    int lane = tid & 63;

    for (int base = beg + (wid << 6); base < end; base += BM_BLOCK) {
        int nk = min(64, end - base);
        unsigned p = (lane < nk) ? packed[base + lane] : 0u;
        int j = 0;
        for (; j + 8 <= nk; j += 8) {
            unsigned q[8];
            float v[8];
            #pragma unroll
            for (int k = 0; k < 8; ++k) q[k] = (unsigned)__shfl((int)p, j + k);
            #pragma unroll
            for (int k = 0; k < 8; ++k) v[k] = h[(q[k] & 0x1FFFFu) * D_FEAT + lane];
            #pragma unroll
            for (int k = 0; k < 8; ++k)
                atomicMax(&buf[(q[k] >> 17) * D_FEAT + lane], enc_f32(v[k]));
        }
        for (; j < nk; ++j) {
            unsigned pj = (unsigned)__shfl((int)p, j);
            float v = h[(pj & 0x1FFFFu) * D_FEAT + lane];
            atomicMax(&buf[(pj >> 17) * D_FEAT + lane], enc_f32(v));
        }
    }
    __syncthreads();

    for (int i = tid; i < nvals; i += BM_BLOCK) {
        unsigned u = buf[i];
        out[node0 * D_FEAT + i] = (u == ENC_NEG_INF) ? 0.0f : dec_f32(u);
    }
}

// ---------- fallback: atomic scatter (round-1 path) ----------
__global__ void init_out_kernel(uint4* __restrict__ out, int n4) {
    int i = blockIdx.x * blockDim.x + threadIdx.x;
    if (i < n4) {
        uint4 v;
        v.x = NEG_INF_BITS; v.y = NEG_INF_BITS; v.z = NEG_INF_BITS; v.w = NEG_INF_BITS;
        out[i] = v;
    }
}
__global__ void scatter_max_kernel(const float* __restrict__ h, const int* __restrict__ src,
                                   const int* __restrict__ dst, float* __restrict__ out, int E) {
    int gid = blockIdx.x * blockDim.x + threadIdx.x;
    int e = gid >> 6;
    if (e >= E) return;
    int lane = gid & 63;
    float v = h[src[e] * D_FEAT + lane];
    int* addr = (int*)(out + dst[e] * D_FEAT + lane);
    if (v >= 0.0f) atomicMax(addr, __float_as_int(v));
    else           atomicMin((unsigned int*)addr, __float_as_uint(v));
}
__global__ void finalize_kernel(float* __restrict__ out, int n) {
    int i = blockIdx.x * blockDim.x + threadIdx.x;
    if (i < n && __float_as_uint(out[i]) == NEG_INF_BITS) out[i] = 0.0f;
}

// ---------- launch ----------
extern "C" void kernel_launch(void* const* d_in, const int* in_sizes, int n_in,
                              void* d_out, int out_size, void* d_ws, size_t ws_size,
                              hipStream_t stream) {
    const float* h = (const float*)d_in[0];
    const int* edge_index = (const int*)d_in[1];
    int E = in_sizes[1] / 2;                 // edge_index is [2, E] row-major
    const int* src = edge_index;
    const int* dst = edge_index + E;
    float* out = (float*)d_out;
    int N = out_size / D_FEAT;

    int B = (N + NPB - 1) >> BSHIFT;

    // tile count: 256 preferred (chunk = E/(T*B) ~ 8 edges), fallback smaller
    int T = 0;
    for (int cand = 256; cand >= 64; cand >>= 1) {
        size_t need = ((size_t)cand * B + B + (B + 1) + (size_t)E) * sizeof(int);
        if (ws_size >= need) { T = cand; break; }
    }

    if (N <= (1 << 17) && B <= MAXB && T > 0) {
        int* counts       = (int*)d_ws;                     // [T*B]
        int* hist         = counts + (size_t)T * B;         // [B]
        int* bucket_start = hist + B;                       // [B+1]
        unsigned* packed  = (unsigned*)(bucket_start + B + 1); // [E]

        int Te = ((E + T - 1) / T + 3) & ~3;                // tile size, mult of 4

        count_kernel<<<T, PP_BLOCK, 0, stream>>>(dst, counts, E, Te, B);
        colscan_kernel<<<(B + 63) / 64, PP_BLOCK, 0, stream>>>(counts, hist, T, B);
        place_kernel<<<T, PP_BLOCK, 0, stream>>>(src, dst, counts, hist, bucket_start,
                                                 packed, E, Te, B);
        bucket_max_kernel<<<B, BM_BLOCK, 0, stream>>>(h, bucket_start, packed, out, N);
    } else {
        int n4 = out_size / 4;
        init_out_kernel<<<(n4 + 255) / 256, 256, 0, stream>>>((uint4*)out, n4);
        long long total = (long long)E * 64;
        scatter_max_kernel<<<(int)((total + 255) / 256), 256, 0, stream>>>(h, src, dst, out, E);
        finalize_kernel<<<(out_size + 255) / 256, 256, 0, stream>>>(out, out_size);
    }
}

// Round 10
// 175.023 us; speedup vs baseline: 1.6407x; 1.0775x over previous
//
#include <hip/hip_runtime.h>

#define D_FEAT 64
#define NEG_INF_BITS 0xFF800000u
#define ENC_NEG_INF  0x007FFFFFu   // order-preserving encoding of -inf
#define NPB 128                     // nodes per bucket (= 1 << BSHIFT)
#define BSHIFT 7
#define BM_BLOCK 512                // bucket_max threads (8 waves)
#define PP_BLOCK 512                // count/place threads
#define MAXB 1024                   // max buckets (N <= 131072)

// Order-preserving float->uint: enc monotone increasing with float value.
__device__ __forceinline__ unsigned enc_f32(float v) {
    unsigned b = __float_as_uint(v);
    return ((int)b >= 0) ? (b ^ 0x80000000u) : ~b;
}
__device__ __forceinline__ float dec_f32(unsigned u) {
    return (u & 0x80000000u) ? __uint_as_float(u ^ 0x80000000u) : __uint_as_float(~u);
}

// ---------- K1: per-tile bucket histogram (LDS only, deterministic) ----------
__global__ void __launch_bounds__(PP_BLOCK)
count_kernel(const int* __restrict__ dst, int* __restrict__ counts,
             int E, int Te, int B) {
    __shared__ int lh[MAXB];
    int tid = threadIdx.x;
    for (int i = tid; i < B; i += PP_BLOCK) lh[i] = 0;
    __syncthreads();
    int t = blockIdx.x;
    int beg = t * Te;
    int end = min(E, beg + Te);
    if ((E & 3) == 0) {
        int n4 = (end > beg) ? ((end - beg) >> 2) : 0;
        const int4* d4 = (const int4*)(dst + beg);     // beg multiple of 4
        for (int k = tid; k < n4; k += PP_BLOCK) {
            int4 d = d4[k];
            atomicAdd(&lh[d.x >> BSHIFT], 1);
            atomicAdd(&lh[d.y >> BSHIFT], 1);
            atomicAdd(&lh[d.z >> BSHIFT], 1);
            atomicAdd(&lh[d.w >> BSHIFT], 1);
        }
        for (int i = beg + (n4 << 2) + tid; i < end; i += PP_BLOCK)
            atomicAdd(&lh[dst[i] >> BSHIFT], 1);
    } else {
        for (int i = beg + tid; i < end; i += PP_BLOCK)
            atomicAdd(&lh[dst[i] >> BSHIFT], 1);
    }
    __syncthreads();
    for (int i = tid; i < B; i += PP_BLOCK) counts[t * B + i] = lh[i];
}

// ---------- K2: column exclusive scan over tiles (64 buckets/block, coalesced) ----------
__global__ void __launch_bounds__(PP_BLOCK)
colscan_kernel(int* __restrict__ counts, int* __restrict__ hist, int T, int B) {
    __shared__ int part[PP_BLOCK / 64][64];
    int lane = threadIdx.x & 63;
    int wid = threadIdx.x >> 6;
    const int NW = PP_BLOCK / 64;
    int b = (blockIdx.x << 6) + lane;
    bool ok = b < B;
    int Tc = (T + NW - 1) / NW;
    int t0 = wid * Tc;
    int t1 = min(T, t0 + Tc);

    int s = 0;
    if (ok) {
        #pragma unroll 4
        for (int t = t0; t < t1; ++t) s += counts[t * B + b];
    }
    part[wid][lane] = s;
    __syncthreads();
    int base = 0, total = 0;
    #pragma unroll
    for (int w = 0; w < NW; ++w) {
        int pv = part[w][lane];
        if (w < wid) base += pv;
        total += pv;
    }
    if (ok) {
        if (wid == 0) hist[b] = total;
        int run = base;
        for (int t = t0; t < t1; ++t) {
            int v = counts[t * B + b];
            counts[t * B + b] = run;
            run += v;
        }
    }
}

// ---------- K3: place (fused local scan of hist -> cursors; plain stores) ----------
__global__ void __launch_bounds__(PP_BLOCK)
place_kernel(const int* __restrict__ src, const int* __restrict__ dst,
             const int* __restrict__ counts, const int* __restrict__ hist,
             int* __restrict__ bucket_start, unsigned* __restrict__ packed,
             int E, int Te, int B) {
    __shared__ int sscan[2 * PP_BLOCK];    // 1024-slot local scan of hist
    __shared__ int lcur[MAXB];             // cursors
    int tid = threadIdx.x;
    int t = blockIdx.x;

    int p0 = tid, p1 = tid + PP_BLOCK;
    int v0 = (p0 < B) ? hist[p0] : 0;
    int v1 = (p1 < B) ? hist[p1] : 0;
    sscan[p0] = v0;
    sscan[p1] = v1;
    __syncthreads();
    for (int off = 1; off < 2 * PP_BLOCK; off <<= 1) {
        int a0 = (p0 >= off) ? sscan[p0 - off] : 0;
        int a1 = (p1 >= off) ? sscan[p1 - off] : 0;
        __syncthreads();
        sscan[p0] += a0;
        sscan[p1] += a1;
        __syncthreads();
    }
    if (t == 0) {                          // publish bucket_start once
        if (p0 < B) bucket_start[p0] = sscan[p0] - v0;
        if (p1 < B) bucket_start[p1] = sscan[p1] - v1;
        if (tid == 0) bucket_start[B] = sscan[B - 1];
    }
    if (p0 < B) lcur[p0] = (sscan[p0] - v0) + counts[t * B + p0];
    if (p1 < B) lcur[p1] = (sscan[p1] - v1) + counts[t * B + p1];
    __syncthreads();

    int beg = t * Te;
    int end = min(E, beg + Te);
    if ((E & 3) == 0) {
        int n4 = (end > beg) ? ((end - beg) >> 2) : 0;
        const int4* d4 = (const int4*)(dst + beg);
        const int4* s4 = (const int4*)(src + beg);
        for (int k = tid; k < n4; k += PP_BLOCK) {
            int4 d = d4[k];
            int4 s = s4[k];
            int q0 = atomicAdd(&lcur[d.x >> BSHIFT], 1);
            packed[q0] = (unsigned)s.x | ((unsigned)(d.x & (NPB - 1)) << 17);
            int q1 = atomicAdd(&lcur[d.y >> BSHIFT], 1);
            packed[q1] = (unsigned)s.y | ((unsigned)(d.y & (NPB - 1)) << 17);
            int q2 = atomicAdd(&lcur[d.z >> BSHIFT], 1);
            packed[q2] = (unsigned)s.z | ((unsigned)(d.z & (NPB - 1)) << 17);
            int q3 = atomicAdd(&lcur[d.w >> BSHIFT], 1);
            packed[q3] = (unsigned)s.w | ((unsigned)(d.w & (NPB - 1)) << 17);
        }
        for (int i = beg + (n4 << 2) + tid; i < end; i += PP_BLOCK) {
            int d = dst[i];
            int pos = atomicAdd(&lcur[d >> BSHIFT], 1);
            packed[pos] = (unsigned)src[i] | ((unsigned)(d & (NPB - 1)) << 17);
        }
    } else {
        for (int i = beg + tid; i < end; i += PP_BLOCK) {
            int d = dst[i];
            int pos = atomicAdd(&lcur[d >> BSHIFT], 1);
            packed[pos] = (unsigned)src[i] | ((unsigned)(d & (NPB - 1)) << 17);
        }
    }
}

// ---------- K4: per-bucket scatter-max in LDS (round-5 winner, unchanged) ----------
__global__ void __launch_bounds__(BM_BLOCK)
bucket_max_kernel(const float* __restrict__ h,
                  const int* __restrict__ bucket_start,
                  const unsigned* __restrict__ packed,
                  float* __restrict__ out, int N) {
    __shared__ unsigned buf[NPB * D_FEAT];   // 32 KB
    int b = blockIdx.x;
    int tid = threadIdx.x;
    int node0 = b << BSHIFT;
    int nvals = (min(NPB, N - node0)) * D_FEAT;

    for (int i = tid; i < NPB * D_FEAT; i += BM_BLOCK) buf[i] = ENC_NEG_INF;
    __syncthreads();

    int beg = bucket_start[b];
    int end = bucket_start[b + 1];
    int wid = tid >> 6;
    int lane = tid & 63;

    for (int base = beg + (wid << 6); base < end; base += BM_BLOCK) {
        int nk = min(64, end - base);
        unsigned p = (lane < nk) ? packed[base + lane] : 0u;
        int j = 0;
        for (; j + 8 <= nk; j += 8) {
            unsigned q[8];
            float v[8];
            #pragma unroll
            for (int k = 0; k < 8; ++k) q[k] = (unsigned)__shfl((int)p, j + k);
            #pragma unroll
            for (int k = 0; k < 8; ++k) v[k] = h[(q[k] & 0x1FFFFu) * D_FEAT + lane];
            #pragma unroll
            for (int k = 0; k < 8; ++k)
                atomicMax(&buf[(q[k] >> 17) * D_FEAT + lane], enc_f32(v[k]));
        }
        for (; j < nk; ++j) {
            unsigned pj = (unsigned)__shfl((int)p, j);
            float v = h[(pj & 0x1FFFFu) * D_FEAT + lane];
            atomicMax(&buf[(pj >> 17) * D_FEAT + lane], enc_f32(v));
        }
    }
    __syncthreads();

    for (int i = tid; i < nvals; i += BM_BLOCK) {
        unsigned u = buf[i];
        out[node0 * D_FEAT + i] = (u == ENC_NEG_INF) ? 0.0f : dec_f32(u);
    }
}

// ---------- fallback: atomic scatter (round-1 path) ----------
__global__ void init_out_kernel(uint4* __restrict__ out, int n4) {
    int i = blockIdx.x * blockDim.x + threadIdx.x;
    if (i < n4) {
        uint4 v;
        v.x = NEG_INF_BITS; v.y = NEG_INF_BITS; v.z = NEG_INF_BITS; v.w = NEG_INF_BITS;
        out[i] = v;
    }
}
__global__ void scatter_max_kernel(const float* __restrict__ h, const int* __restrict__ src,
                                   const int* __restrict__ dst, float* __restrict__ out, int E) {
    int gid = blockIdx.x * blockDim.x + threadIdx.x;
    int e = gid >> 6;
    if (e >= E) return;
    int lane = gid & 63;
    float v = h[src[e] * D_FEAT + lane];
    int* addr = (int*)(out + dst[e] * D_FEAT + lane);
    if (v >= 0.0f) atomicMax(addr, __float_as_int(v));
    else           atomicMin((unsigned int*)addr, __float_as_uint(v));
}
__global__ void finalize_kernel(float* __restrict__ out, int n) {
    int i = blockIdx.x * blockDim.x + threadIdx.x;
    if (i < n && __float_as_uint(out[i]) == NEG_INF_BITS) out[i] = 0.0f;
}

// ---------- launch ----------
extern "C" void kernel_launch(void* const* d_in, const int* in_sizes, int n_in,
                              void* d_out, int out_size, void* d_ws, size_t ws_size,
                              hipStream_t stream) {
    const float* h = (const float*)d_in[0];
    const int* edge_index = (const int*)d_in[1];
    int E = in_sizes[1] / 2;                 // edge_index is [2, E] row-major
    const int* src = edge_index;
    const int* dst = edge_index + E;
    float* out = (float*)d_out;
    int N = out_size / D_FEAT;

    int B = (N + NPB - 1) >> BSHIFT;

    // tile count: 512 preferred (2 blocks/CU for count/place), fallback smaller
    int T = 0;
    for (int cand = 512; cand >= 64; cand >>= 1) {
        size_t need = ((size_t)cand * B + B + (B + 1) + (size_t)E) * sizeof(int);
        if (ws_size >= need) { T = cand; break; }
    }

    if (N <= (1 << 17) && B <= MAXB && T > 0) {
        int* counts       = (int*)d_ws;                     // [T*B]
        int* hist         = counts + (size_t)T * B;         // [B]
        int* bucket_start = hist + B;                       // [B+1]
        unsigned* packed  = (unsigned*)(bucket_start + B + 1); // [E]

        int Te = ((E + T - 1) / T + 3) & ~3;                // tile size, mult of 4

        count_kernel<<<T, PP_BLOCK, 0, stream>>>(dst, counts, E, Te, B);
        colscan_kernel<<<(B + 63) / 64, PP_BLOCK, 0, stream>>>(counts, hist, T, B);
        place_kernel<<<T, PP_BLOCK, 0, stream>>>(src, dst, counts, hist, bucket_start,
                                                 packed, E, Te, B);
        bucket_max_kernel<<<B, BM_BLOCK, 0, stream>>>(h, bucket_start, packed, out, N);
    } else {
        int n4 = out_size / 4;
        init_out_kernel<<<(n4 + 255) / 256, 256, 0, stream>>>((uint4*)out, n4);
        long long total = (long long)E * 64;
        scatter_max_kernel<<<(int)((total + 255) / 256), 256, 0, stream>>>(h, src, dst, out, E);
        finalize_kernel<<<(out_size + 255) / 256, 256, 0, stream>>>(out, out_size);
    }
}